// Round 5
// baseline (138.533 us; speedup 1.0000x reference)
//
#include <hip/hip_runtime.h>
#include <hip/hip_cooperative_groups.h>
#include <math.h>

namespace cg = cooperative_groups;

// N=16384, D=64, C=64.
// loss = 1 - (1/n_unique) * sum_c [ (||S_c||^2 - n_c) / (n_c (n_c - 1)) ]
// where S_c = sum of row-normalized feature rows of class c.
//
// ONE cooperative dispatch, 16 blocks x 1024 threads, ONE grid.sync:
//   phase1: each block accumulates 1024 rows into LDS class matrix, writes
//           block-private partial to ws (fully written every call -> no init,
//           no atomics, graph-replay deterministic).
//   sync  : 16-block grid barrier (cheap at 16 arrivals).
//   phase2: block 0 reduces the 16 partials in registers (16 threads/class,
//           4 dims each, dwordx4 coalesced), emits the scalar.

#define NCLS 64
#define DIM 64
#define NB 16
#define THREADS 1024
#define ROWS_PER_BLOCK 1024   // 16384 / 16

__global__ __launch_bounds__(THREADS) void cpl_one(
    const float* __restrict__ feat,   // [n, DIM]
    const int* __restrict__ pred,     // [n]
    float* __restrict__ partial,      // ws: [NB, NCLS*DIM]
    float* __restrict__ cntp,         // ws: [NB, NCLS]
    float* __restrict__ out,          // [1]
    int n)
{
    cg::grid_group grid = cg::this_grid();
    const int tid = threadIdx.x;

    // ---------- phase 1: block-local class accumulation ----------
    __shared__ float s_acc[NCLS * DIM];
    __shared__ float s_cnt[NCLS];
    for (int i = tid; i < NCLS * DIM; i += THREADS) s_acc[i] = 0.0f;
    if (tid < NCLS) s_cnt[tid] = 0.0f;
    __syncthreads();

    const int lane = tid & 63;
    const int wave = tid >> 6;                                // 0..15
    const int rpw  = ROWS_PER_BLOCK / (THREADS / 64);         // 64
    const int row0 = blockIdx.x * ROWS_PER_BLOCK + wave * rpw;

    for (int r = row0; r < row0 + rpw; ++r) {
        if (r >= n) break;
        float x = feat[(size_t)r * DIM + lane];               // coalesced
        float s = x * x;
        #pragma unroll
        for (int off = 32; off; off >>= 1) s += __shfl_xor(s, off, 64);
        float v = x / sqrtf(s);                               // normalized
        int c = pred[r];                                      // wave-uniform
        atomicAdd(&s_acc[c * DIM + lane], v);                 // LDS atomic
        if (lane == 0) atomicAdd(&s_cnt[c], 1.0f);
    }
    __syncthreads();

    // Block-private partial: no init needed, deterministic across replays.
    float* p = partial + (size_t)blockIdx.x * (NCLS * DIM);
    for (int i = tid; i < NCLS * DIM; i += THREADS) p[i] = s_acc[i];
    if (tid < NCLS) cntp[blockIdx.x * NCLS + tid] = s_cnt[tid];

    __threadfence();
    grid.sync();   // 16-block barrier

    // ---------- phase 2: block 0 reduces 16 partials ----------
    if (blockIdx.x != 0) return;

    __shared__ float s_cnt2[NCLS];
    __shared__ float s_avg[NCLS];
    __shared__ float s_pres[NCLS];

    if (tid < NCLS) {
        float c = 0.0f;
        #pragma unroll
        for (int b = 0; b < NB; ++b) c += cntp[b * NCLS + tid];
        s_cnt2[tid] = c;
    }

    // 16 threads per class, 4 dims each, totals kept in registers.
    const int c  = tid >> 4;          // class 0..63
    const int pp = tid & 15;          // dim group
    float t0 = 0.0f, t1 = 0.0f, t2 = 0.0f, t3 = 0.0f;
    #pragma unroll
    for (int b = 0; b < NB; ++b) {
        const float* src = partial + (size_t)b * (NCLS * DIM) + c * DIM + pp * 4;
        t0 += src[0]; t1 += src[1]; t2 += src[2]; t3 += src[3];
    }
    float s = t0 * t0 + t1 * t1 + t2 * t2 + t3 * t3;
    s += __shfl_xor(s, 1, 64);
    s += __shfl_xor(s, 2, 64);
    s += __shfl_xor(s, 4, 64);
    s += __shfl_xor(s, 8, 64);
    __syncthreads();                  // s_cnt2 ready
    if (pp == 0) {
        float nc = s_cnt2[c];
        s_avg[c]  = (nc > 1.5f) ? (s - nc) / (nc * (nc - 1.0f)) : 0.0f;
        s_pres[c] = (nc > 0.5f) ? 1.0f : 0.0f;
    }
    __syncthreads();

    if (tid < 64) {
        float a  = s_avg[tid];
        float pr = s_pres[tid];
        #pragma unroll
        for (int off = 32; off; off >>= 1) {
            a  += __shfl_xor(a, off, 64);
            pr += __shfl_xor(pr, off, 64);
        }
        if (tid == 0) out[0] = 1.0f - a / pr;
    }
}

extern "C" void kernel_launch(void* const* d_in, const int* in_sizes, int n_in,
                              void* d_out, int out_size, void* d_ws, size_t ws_size,
                              hipStream_t stream) {
    const float* feat = (const float*)d_in[0];
    const int*   pred = (const int*)d_in[1];
    float* out = (float*)d_out;
    int n = in_sizes[1];                                 // 16384

    float* partial = (float*)d_ws;                        // NB * 4096 floats
    float* cntp    = partial + (size_t)NB * (NCLS * DIM); // NB * 64 floats

    void* args[] = { (void*)&feat, (void*)&pred, (void*)&partial,
                     (void*)&cntp, (void*)&out, (void*)&n };
    hipLaunchCooperativeKernel((const void*)cpl_one, dim3(NB), dim3(THREADS),
                               args, 0, stream);
}

// Round 6
// 27.425 us; speedup vs baseline: 5.0513x; 5.0513x over previous
//
#include <hip/hip_runtime.h>
#include <math.h>

// N=16384, D=64, C=64.
// loss = 1 - (1/n_unique) * sum_c [ (||S_c||^2 - n_c) / (n_c (n_c - 1)) ]
// where S_c = sum of row-normalized feature rows of class c.
//
// 3 graph nodes: memset(16.6KB) -> phase1 (128 blk x 512 thr, float4-row
// vectorized, LDS accumulate + device-atomic flush) -> finish (1 blk x 256).

#define NCLS 64
#define DIM 64
#define NB 128
#define THREADS 512
#define ROWS_PER_BLOCK 128            // 16384 / NB
#define ACC_FLOATS (NCLS * DIM + NCLS)

__global__ __launch_bounds__(THREADS) void cpl_phase1(
    const float* __restrict__ feat,   // [n, DIM]
    const int* __restrict__ pred,     // [n]
    float* __restrict__ acc,          // [NCLS*DIM], pre-zeroed
    float* __restrict__ cnt,          // [NCLS], pre-zeroed
    int n)
{
    __shared__ float s_acc[NCLS * DIM];
    __shared__ float s_cnt[NCLS];
    const int tid = threadIdx.x;

    for (int i = tid; i < NCLS * DIM; i += THREADS) s_acc[i] = 0.0f;
    if (tid < NCLS) s_cnt[tid] = 0.0f;
    __syncthreads();

    const int lane = tid & 63;
    const int wave = tid >> 6;                         // 0..7
    const int rpw  = ROWS_PER_BLOCK / (THREADS / 64);  // 16 rows per wave
    const int row0 = blockIdx.x * ROWS_PER_BLOCK + wave * rpw;
    const int g = lane >> 4;                           // row subgroup 0..3
    const int q = lane & 15;                           // dim quad 0..15

    #pragma unroll
    for (int it = 0; it < rpw / 4; ++it) {             // 4 float4 iterations
        const int rbase = row0 + it * 4;               // wave covers 4 rows
        if (rbase + 3 < n) {
            // lane l -> row rbase+g, dims 4q..4q+3 (one dwordx4, fully coalesced)
            float4 v = *(const float4*)(feat + (size_t)rbase * DIM + lane * 4);
            float s = v.x * v.x + v.y * v.y + v.z * v.z + v.w * v.w;
            s += __shfl_xor(s, 1, 64);                 // reduce within 16-lane group
            s += __shfl_xor(s, 2, 64);
            s += __shfl_xor(s, 4, 64);
            s += __shfl_xor(s, 8, 64);
            float r = rsqrtf(s);
            int c = pred[rbase + g];                   // group-uniform broadcast
            float* dst = &s_acc[c * DIM + q * 4];
            atomicAdd(dst + 0, v.x * r);
            atomicAdd(dst + 1, v.y * r);
            atomicAdd(dst + 2, v.z * r);
            atomicAdd(dst + 3, v.w * r);
            if (q == 0) atomicAdd(&s_cnt[c], 1.0f);
        } else {
            // tail fallback (never taken for n=16384): scalar per-row
            for (int r = rbase; r < rbase + 4 && r < n; ++r) {
                float x = feat[(size_t)r * DIM + lane];
                float s = x * x;
                #pragma unroll
                for (int off = 32; off; off >>= 1) s += __shfl_xor(s, off, 64);
                float vv = x * rsqrtf(s);
                int c = pred[r];
                atomicAdd(&s_acc[c * DIM + lane], vv);
                if (lane == 0) atomicAdd(&s_cnt[c], 1.0f);
            }
        }
    }
    __syncthreads();

    // Flush block-local sums (skip zeros: ~35-40% of slots untouched).
    for (int i = tid; i < NCLS * DIM; i += THREADS) {
        float v = s_acc[i];
        if (v != 0.0f) atomicAdd(&acc[i], v);
    }
    if (tid < NCLS) {
        float v = s_cnt[tid];
        if (v != 0.0f) atomicAdd(&cnt[tid], v);
    }
}

__global__ __launch_bounds__(256) void cpl_finish(
    const float* __restrict__ acc,   // [NCLS*DIM]
    const float* __restrict__ cnt,   // [NCLS]
    float* __restrict__ out)         // [1]
{
    __shared__ float s_avg[NCLS];
    __shared__ float s_pres[NCLS];
    const int t = threadIdx.x;
    const int c = t >> 2;            // 4 threads per class
    const int part = t & 3;

    const float4* src = (const float4*)(acc + c * DIM + part * 16);
    float s = 0.0f;
    #pragma unroll
    for (int k = 0; k < 4; ++k) {
        float4 v = src[k];
        s += v.x * v.x + v.y * v.y + v.z * v.z + v.w * v.w;
    }
    s += __shfl_xor(s, 1, 64);
    s += __shfl_xor(s, 2, 64);
    if (part == 0) {
        float nc = cnt[c];
        s_avg[c]  = (nc > 1.5f) ? (s - nc) / (nc * (nc - 1.0f)) : 0.0f;
        s_pres[c] = (nc > 0.5f) ? 1.0f : 0.0f;
    }
    __syncthreads();
    if (t < 64) {
        float a  = s_avg[t];
        float pr = s_pres[t];
        #pragma unroll
        for (int off = 32; off; off >>= 1) {
            a  += __shfl_xor(a, off, 64);
            pr += __shfl_xor(pr, off, 64);
        }
        if (t == 0) out[0] = 1.0f - a / pr;
    }
}

extern "C" void kernel_launch(void* const* d_in, const int* in_sizes, int n_in,
                              void* d_out, int out_size, void* d_ws, size_t ws_size,
                              hipStream_t stream) {
    const float* feat = (const float*)d_in[0];
    const int*   pred = (const int*)d_in[1];
    float* out = (float*)d_out;
    const int n = in_sizes[1];                 // 16384

    float* acc = (float*)d_ws;                 // NCLS*DIM floats
    float* cnt = acc + NCLS * DIM;             // NCLS floats

    hipMemsetAsync(acc, 0, ACC_FLOATS * sizeof(float), stream);
    cpl_phase1<<<NB, THREADS, 0, stream>>>(feat, pred, acc, cnt, n);
    cpl_finish<<<1, 256, 0, stream>>>(acc, cnt, out);
}